// Round 2
// baseline (55.914 us; speedup 1.0000x reference)
//
#include <hip/hip_runtime.h>
#include <hip/hip_bf16.h>

typedef __attribute__((ext_vector_type(8))) short bf16x8;
typedef __attribute__((ext_vector_type(4))) float f32x4;

__device__ __forceinline__ short f2bf(float f) {
    union { float f; unsigned u; } v; v.f = f;
    unsigned r = v.u + 0x7fffu + ((v.u >> 16) & 1u);
    return (short)(r >> 16);
}

#define KP  800   // K padded 784 -> 800 (25 * 32)
#define LDK 40    // LDS row length in bf16 (32 + 8 pad, keeps 16B align, ~2-way banks)
#define NKT 25    // K-steps

// ---------------- init: transpose/convert weights, pointer tables ----------------
__global__ void init_kernel(const float* __restrict__ W1, const float* __restrict__ W2,
                            const float* __restrict__ Wp, const float* __restrict__ bp,
                            const float* __restrict__ Wr1, const float* __restrict__ br1,
                            const float* __restrict__ Wr2, const float* __restrict__ br2,
                            short* __restrict__ w1t, short* __restrict__ w2t,
                            float* __restrict__ ptabs)
{
    int tid = blockIdx.x * blockDim.x + threadIdx.x;
    int stride = gridDim.x * blockDim.x;
    // w1t[n][k] = W1[k][n], K zero-padded to 800
    for (int i = tid; i < 256 * KP; i += stride) {
        int n = i / KP, k = i - n * KP;
        float v = (k < 784) ? W1[k * 256 + n] : 0.f;
        w1t[i] = f2bf(v);
    }
    // w2t[n][k] = W2[k][n], N zero-padded to 16
    for (int i = tid; i < 16 * 256; i += stride) {
        int n = i >> 8, k = i & 255;
        float v = (n < 10) ? W2[k * 10 + n] : 0.f;
        w2t[i] = f2bf(v);
    }
    // pointer tables: only 4 possible programs
    if (blockIdx.x == 0 && threadIdx.x < 8) {
        int which = threadIdx.x >> 2, p = threadIdx.x & 3;
        const float* Wr = which ? Wr2 : Wr1;
        const float* br = which ? br2 : br1;
        float s[4];
        for (int q = 0; q < 4; q++) {
            float a = br[q];
            for (int j = 0; j < 16; j++) a += (Wp[p * 16 + j] + bp[j]) * Wr[j * 4 + q];
            s[q] = a;
        }
        float m = fmaxf(fmaxf(s[0], s[1]), fmaxf(s[2], s[3]));
        float e[4]; float tot = 0.f;
        for (int q = 0; q < 4; q++) { e[q] = __expf(s[q] - m); tot += e[q]; }
        for (int q = 0; q < 4; q++) ptabs[which * 16 + p * 4 + q] = e[q] / tot;
    }
}

// ---------------- fused main kernel ----------------
// 512 blocks x 512 threads (8 waves, 2x4 wave grid). Tile: 128 rows x 256 cols, BK=32.
__global__ __launch_bounds__(512, 4) void fused_kernel(
    const float* __restrict__ g_in, const float* __restrict__ onehot,
    const float* __restrict__ b1g, const float* __restrict__ b2g,
    const short* __restrict__ w1t, const short* __restrict__ w2t,
    const float* __restrict__ ptabs, float* __restrict__ out)
{
    __shared__ __align__(16) char lds[78464];
    short* Abuf = (short*)lds;                  // 2 x 128 x LDK bf16 = 20480 B
    short* Bbuf = (short*)(lds + 20480);        // 2 x 256 x LDK bf16 = 40960 B
    short* h1   = (short*)lds;                  // overlay: 128 x 264 bf16 = 67584 B
    float* probs = (float*)(lds + 67584);       // 128 x 16 f32 = 8192 B
    float* dist1 = (float*)(lds + 75776);       // 32 x 10 f32
    float* dist2 = (float*)(lds + 77056);       // 32 x 10 f32 (ends 78336)

    const int t = threadIdx.x;
    const int lane = t & 63, wave = t >> 6;
    const int l16 = lane & 15, lg = lane >> 4;
    const int wr = wave >> 2, wc = wave & 3;
    const int blk = blockIdx.x;

    // staging coords: A: thread -> (row, 8-float chunk); B: thread -> (n-row, 16-bf16 half)
    const int ar = t >> 2, aq = t & 3;
    const int bn = t >> 1, bh = t & 1;
    const float* gA = g_in + ((long)blk * 128 + ar) * 784 + aq * 8;
    const short* gB = w1t + bn * KP + bh * 16;
    short* awp = Abuf + ar * LDK + aq * 8;
    short* bwp = Bbuf + bn * LDK + bh * 16;

    f32x4 acc[4][4];
    #pragma unroll
    for (int mi = 0; mi < 4; mi++)
        #pragma unroll
        for (int ni = 0; ni < 4; ni++)
            acc[mi][ni] = (f32x4)0.f;

    f32x4 x0, x1; bf16x8 y0, y1;
    auto load_tile = [&](int kt) {
        const int k0 = kt * 32;
        if (k0 + aq * 8 < 784) {           // chunks are 8-aligned: fully valid or fully pad
            x0 = *(const f32x4*)(gA + k0);
            x1 = *(const f32x4*)(gA + k0 + 4);
        } else { x0 = (f32x4)0.f; x1 = (f32x4)0.f; }
        y0 = *(const bf16x8*)(gB + k0);
        y1 = *(const bf16x8*)(gB + k0 + 8);
    };
    auto write_tile = [&](int buf) {
        bf16x8 a8;
        a8[0] = f2bf(x0[0]); a8[1] = f2bf(x0[1]); a8[2] = f2bf(x0[2]); a8[3] = f2bf(x0[3]);
        a8[4] = f2bf(x1[0]); a8[5] = f2bf(x1[1]); a8[6] = f2bf(x1[2]); a8[7] = f2bf(x1[3]);
        *(bf16x8*)(awp + buf * (128 * LDK)) = a8;
        *(bf16x8*)(bwp + buf * (256 * LDK)) = y0;
        *(bf16x8*)(bwp + buf * (256 * LDK) + 8) = y1;
    };

    // ---- GEMM1: h1 = relu(grid @ W1 + b1), double-buffered ----
    load_tile(0); write_tile(0);
    __syncthreads();
    int cur = 0;
    for (int kt = 0; kt < NKT; kt++) {
        const bool more = (kt + 1 < NKT);
        if (more) load_tile(kt + 1);       // issue global loads early (latency under MFMA)
        const short* ab = Abuf + cur * (128 * LDK);
        const short* bb = Bbuf + cur * (256 * LDK);
        bf16x8 aF[4], bF[4];
        #pragma unroll
        for (int mi = 0; mi < 4; mi++)
            aF[mi] = *(const bf16x8*)(ab + (wr * 64 + mi * 16 + l16) * LDK + lg * 8);
        #pragma unroll
        for (int ni = 0; ni < 4; ni++)
            bF[ni] = *(const bf16x8*)(bb + (wc * 64 + ni * 16 + l16) * LDK + lg * 8);
        #pragma unroll
        for (int mi = 0; mi < 4; mi++)
            #pragma unroll
            for (int ni = 0; ni < 4; ni++)
                acc[mi][ni] = __builtin_amdgcn_mfma_f32_16x16x32_bf16(aF[mi], bF[ni], acc[mi][ni], 0, 0, 0);
        if (more) write_tile(cur ^ 1);
        __syncthreads();
        cur ^= 1;
    }

    // ---- epilogue 1: relu + bias -> h1 (bf16) in LDS (overlays gemm buffers) ----
    #pragma unroll
    for (int mi = 0; mi < 4; mi++) {
        const int R = wr * 64 + mi * 16 + lg * 4;
        #pragma unroll
        for (int ni = 0; ni < 4; ni++) {
            const int N = wc * 64 + ni * 16 + l16;
            const float bias = b1g[N];
            #pragma unroll
            for (int j = 0; j < 4; j++) {
                float v = acc[mi][ni][j] + bias;
                h1[(R + j) * 264 + N] = f2bf(fmaxf(v, 0.f));
            }
        }
    }
    __syncthreads();

    // ---- GEMM2: logits = h1 @ W2 (+b2), wave w owns rows 16w..16w+15, N=16 (10 valid) ----
    f32x4 acc2 = (f32x4)0.f;
    const short* h1r = h1 + (wave * 16 + l16) * 264 + lg * 8;
    const short* w2r = w2t + l16 * 256 + lg * 8;
    #pragma unroll
    for (int kk = 0; kk < 8; kk++) {
        bf16x8 a2 = *(const bf16x8*)(h1r + kk * 32);
        bf16x8 b2f = *(const bf16x8*)(w2r + kk * 32);
        acc2 = __builtin_amdgcn_mfma_f32_16x16x32_bf16(a2, b2f, acc2, 0, 0, 0);
    }

    // ---- softmax(logits / 0.1) per row; C frag: row = lg*4+j, col = l16 ----
    const float b2v = (l16 < 10) ? b2g[l16] : 0.f;
    float pv[4], mx[4];
    #pragma unroll
    for (int j = 0; j < 4; j++) {
        pv[j] = (l16 < 10) ? (acc2[j] + b2v) * 10.f : -1e30f;
        mx[j] = pv[j];
    }
    #pragma unroll
    for (int off = 1; off < 16; off <<= 1)
        #pragma unroll
        for (int j = 0; j < 4; j++)
            mx[j] = fmaxf(mx[j], __shfl_xor(mx[j], off));
    float ex[4], sm[4];
    #pragma unroll
    for (int j = 0; j < 4; j++) { ex[j] = __expf(pv[j] - mx[j]); sm[j] = ex[j]; }
    #pragma unroll
    for (int off = 1; off < 16; off <<= 1)
        #pragma unroll
        for (int j = 0; j < 4; j++)
            sm[j] += __shfl_xor(sm[j], off);
    #pragma unroll
    for (int j = 0; j < 4; j++)
        probs[(wave * 16 + lg * 4 + j) * 16 + l16] = ex[j] / sm[j];
    __syncthreads();

    // ---- pointer mix: dist1/dist2 (32 samples x 10 digits) ----
    if (t < 320) {
        int s = t / 10, d = t - s * 10;
        const float* oh = onehot + ((long)blk * 32 + s) * 4;
        int pid = (int)(oh[1] + 2.f * oh[2] + 3.f * oh[3] + 0.5f);
        const float* p1t = ptabs + pid * 4;
        const float* p2t = ptabs + 16 + pid * 4;
        float d1 = 0.f, d2 = 0.f;
        #pragma unroll
        for (int p = 0; p < 4; p++) {
            float pr = probs[(s * 4 + p) * 16 + d];
            d1 += p1t[p] * pr;
            d2 += p2t[p] * pr;
        }
        dist1[s * 10 + d] = d1;
        dist2[s * 10 + d] = d2;
    }
    __syncthreads();

    // ---- conv (i+j==k is symmetric: symmetrization is a no-op) + log ----
    // 608 outputs per block > 512 threads: grid-stride over the block's threads.
    for (int idx = t; idx < 608; idx += 512) {
        int s = idx / 19, k = idx - s * 19;
        int ilo = k > 9 ? k - 9 : 0;
        int ihi = k < 9 ? k : 9;
        float sum = 0.f;
        for (int i = ilo; i <= ihi; i++)
            sum += dist1[s * 10 + i] * dist2[s * 10 + (k - i)];
        out[((long)blk * 32 + s) * 19 + k] = __logf(sum + 1e-10f);
    }
}

extern "C" void kernel_launch(void* const* d_in, const int* in_sizes, int n_in,
                              void* d_out, int out_size, void* d_ws, size_t ws_size,
                              hipStream_t stream)
{
    const float* grid   = (const float*)d_in[0];
    const float* onehot = (const float*)d_in[1];
    const float* W1  = (const float*)d_in[2];
    const float* b1  = (const float*)d_in[3];
    const float* W2  = (const float*)d_in[4];
    const float* b2  = (const float*)d_in[5];
    const float* Wp  = (const float*)d_in[6];
    const float* bp  = (const float*)d_in[7];
    const float* Wr1 = (const float*)d_in[8];
    const float* br1 = (const float*)d_in[9];
    const float* Wr2 = (const float*)d_in[10];
    const float* br2 = (const float*)d_in[11];
    float* out = (float*)d_out;

    short* w1t = (short*)d_ws;              // 256 x 800 bf16 = 409600 B
    short* w2t = w1t + 256 * KP;            // 16 x 256 bf16  = 8192 B
    float* ptabs = (float*)(w2t + 16 * 256);// 2 x 4 x 4 f32  = 128 B

    init_kernel<<<256, 256, 0, stream>>>(W1, W2, Wp, bp, Wr1, br1, Wr2, br2, w1t, w2t, ptabs);

    const int B = in_sizes[1] / 4;          // 16384
    const int nblk = (B * 4) / 128;         // 512
    fused_kernel<<<nblk, 512, 0, stream>>>(grid, onehot, b1, b2, w1t, w2t, ptabs, out);
}